// Round 1
// baseline (238.286 us; speedup 1.0000x reference)
//
#include <hip/hip_runtime.h>
#include <math.h>

// Problem constants
#define BB   16
#define CC   256
#define HW   1024          // 32*32
#define NN   16384         // BB*HW tokens
#define DD   256           // dim
#define KK   8192          // codes
#define ZQ_SIZE 4194304    // 16*256*1024
#define MARGIN 0.017f      // rigorous bf16-score error envelope (bound 0.0156)
#define GCAP 8192          // per-group candidate-token capacity (overflow -> fullscan)
#define RSPLIT 8           // rescore blocks per group (load-balance)

typedef __attribute__((ext_vector_type(8))) short short8;  // 8 bf16 (4 VGPRs)
typedef __attribute__((ext_vector_type(4))) float f32x4;

static __device__ inline unsigned short f2bf(float x) {
    unsigned int u = __float_as_uint(x);
    unsigned int r = (u + 0x7fff + ((u >> 16) & 1)) >> 16;   // RNE
    return (unsigned short)r;
}

static __device__ inline unsigned long long pack_key(float s, int k) {
    unsigned int bits = __float_as_uint(s);
    unsigned int o = (bits & 0x80000000u) ? ~bits : (bits | 0x80000000u);
    return ((unsigned long long)o << 32) | (unsigned int)(~k);
}

// ---------------------------------------------------------------------------
// Kernel 1: wsq (VERBATIM R4 chain — FROZEN: knife-edge fp32 argmax contract;
// R5/R6 reordered this sum and deterministically flipped one token's idx)
// + wb bf16 blob (verbatim body, blocks 0..1023) fused in one W pass.
// Block 0 zeroes gcnt/oflow.
__global__ __launch_bounds__(256) void wsqwb_kernel(const float* __restrict__ W,
                                                    float* __restrict__ wsq,
                                                    unsigned short* __restrict__ wb,
                                                    int* __restrict__ gcnt,
                                                    int* __restrict__ oflow) {
    if (blockIdx.x == 0) {
        gcnt[threadIdx.x] = 0;
        if (threadIdx.x == 0) *oflow = 0;
    }
    {   // --- wsq part: FROZEN summation order (float4 at lane*4, 64-lane tree)
        const int lane = threadIdx.x & 63;
        const int k = blockIdx.x * 4 + (threadIdx.x >> 6);
        float4 v = *(const float4*)(W + (size_t)k * DD + lane * 4);
        float s = v.x * v.x + v.y * v.y + v.z * v.z + v.w * v.w;
        #pragma unroll
        for (int off = 32; off; off >>= 1) s += __shfl_down(s, off);
        if (lane == 0) wsq[k] = s;
    }
    if (blockIdx.x < 1024) {   // --- wb part: verbatim R4 wb_convert body
        const int ch = blockIdx.x * 256 + threadIdx.x;     // 0..262143
        const int c = (ch >> 7) & 7;
        const int r = ch & 127;
        const int kt = ch >> 12, dc = (ch >> 10) & 3;
        const int k = kt * 128 + r;
        const int d0 = dc * 64 + c * 8;
        const float4 v0 = *(const float4*)(W + (size_t)k * DD + d0);
        const float4 v1 = *(const float4*)(W + (size_t)k * DD + d0 + 4);
        uint4 out;
        out.x = (unsigned int)f2bf(v0.x) | ((unsigned int)f2bf(v0.y) << 16);
        out.y = (unsigned int)f2bf(v0.z) | ((unsigned int)f2bf(v0.w) << 16);
        out.z = (unsigned int)f2bf(v1.x) | ((unsigned int)f2bf(v1.y) << 16);
        out.w = (unsigned int)f2bf(v1.z) | ((unsigned int)f2bf(v1.w) << 16);
        *(uint4*)(wb + (size_t)ch * 8) = out;
    }
}

// ---------------------------------------------------------------------------
// Kernel 2: transpose + l2-normalize. Same tile cells / sum order / division
// as the passing R7 version (bit-identical values); only the z-load is
// vectorized to float4 (hw-contiguous).
__global__ __launch_bounds__(256) void normalize_kernel(const float* __restrict__ z,
                                                        float* __restrict__ zn,
                                                        float* __restrict__ znsq,
                                                        unsigned short* __restrict__ zb) {
    __shared__ float tile[64][257];
    __shared__ float s_nrm[64];
    const int t   = threadIdx.x;
    const int b   = blockIdx.x >> 4;
    const int hw0 = (blockIdx.x & 15) * 64;

    #pragma unroll
    for (int cg = 0; cg < 16; ++cg) {
        int c  = cg * 16 + (t >> 4);
        int hw = (t & 15) * 4;
        float4 v = *(const float4*)(z + ((size_t)(b * CC + c) << 10) + hw0 + hw);
        tile[hw + 0][c] = v.x;
        tile[hw + 1][c] = v.y;
        tile[hw + 2][c] = v.z;
        tile[hw + 3][c] = v.w;
    }
    __syncthreads();
    if (t < 64) {
        float s = 0.f;
        #pragma unroll 8
        for (int c = 0; c < 256; ++c) { float v = tile[t][c]; s += v * v; }
        float nrm = sqrtf(s);
        nrm = fmaxf(nrm, 1e-12f);
        s_nrm[t] = nrm;
        znsq[(size_t)b * HW + hw0 + t] = s / (nrm * nrm);
    }
    __syncthreads();
    const int n0 = b * HW + hw0;           // multiple of 64
    for (int r = 0; r < 64; ++r) {
        zn[(size_t)(n0 + r) * DD + t] = tile[r][t] / s_nrm[r];
    }
    const int r    = t & 63;
    const int mt   = n0 >> 7;
    const int rg   = (n0 & 127) + r;
    const float nrm = s_nrm[r];
    #pragma unroll
    for (int loop = 0; loop < 8; ++loop) {
        int comb = loop * 4 + (t >> 6);    // 0..31
        int dc = comb >> 3, c = comb & 7;
        int d0 = dc * 64 + c * 8;
        uint4 out;
        out.x = (unsigned int)f2bf(tile[r][d0 + 0] / nrm) | ((unsigned int)f2bf(tile[r][d0 + 1] / nrm) << 16);
        out.y = (unsigned int)f2bf(tile[r][d0 + 2] / nrm) | ((unsigned int)f2bf(tile[r][d0 + 3] / nrm) << 16);
        out.z = (unsigned int)f2bf(tile[r][d0 + 4] / nrm) | ((unsigned int)f2bf(tile[r][d0 + 5] / nrm) << 16);
        out.w = (unsigned int)f2bf(tile[r][d0 + 6] / nrm) | ((unsigned int)f2bf(tile[r][d0 + 7] / nrm) << 16);
        *(uint4*)(zb + (size_t)(mt * 4 + dc) * 8192 + (size_t)(c * 128 + rg) * 8) = out;
    }
}

// ---------------------------------------------------------------------------
// Kernel 3: MFMA scorer, 256x256 tile, 8 waves (2 code-halves x 4 token-
// quarters), phase-split schedule with counted vmcnt (T3+T4) + setprio (T5).
// Per-element MFMA accumulation order over (dc, ks) is IDENTICAL to the
// previous 128^2 version -> cmax values are bit-identical; only block/wave
// decomposition and scheduling changed (margin-buffered anyway).
// LDS blob layout is MFMA-native (16B/lane contiguous) -> no swizzle needed
// (measured 16 conflicts/block in the 128^2 version).
__global__ __launch_bounds__(512, 2) void score_kernel(const unsigned short* __restrict__ zb,
                                                       const unsigned short* __restrict__ wb,
                                                       const float* __restrict__ wsqv,
                                                       float* __restrict__ cmax) {
    __shared__ __align__(16) unsigned short sT[2][16384];  // tokens: [dbuf][2 halves x 8192]
    __shared__ __align__(16) unsigned short sC[2][16384];  // codes
    __shared__ float rowbuf[8][260];                       // [group col][token] (260: bank-spread)
    __shared__ __align__(16) float swsq[256];

    const int tid  = threadIdx.x;
    const int w    = tid >> 6;          // 0..7
    const int lane = tid & 63;
    const int wr   = w >> 2;            // code half (128 codes)
    const int wc   = w & 3;             // token quarter (64 tokens)
    const int q    = lane >> 4, c15 = lane & 15;
    const int kt   = blockIdx.x & 31;   // code tile of 256
    const int mt   = blockIdx.x >> 5;   // token tile of 256
    const int mtb  = mt * 8;            // zb blob base (2 row-halves x 4 dc)
    const int ktb  = kt * 8;            // wb blob base

    if (tid < 256) swsq[tid] = wsqv[kt * 256 + tid];

    // staging: wave pair -> one 16KB blob; 8 x 1KB wave-ops each
    const int sh = (w >> 1) & 1;        // blob half (rows 0..127 vs 128..255)
    auto stage = [&](int bf, int dc) {
        const unsigned short* gs = (w < 4)
            ? (zb + (size_t)(mtb + sh * 4 + dc) * 8192)
            : (wb + (size_t)(ktb + sh * 4 + dc) * 8192);
        unsigned short* ld = (w < 4) ? &sT[bf][sh * 8192] : &sC[bf][sh * 8192];
        #pragma unroll
        for (int i = 0; i < 8; ++i) {
            const int eo = ((w & 1) * 8 + i) << 9;   // shorts
            __builtin_amdgcn_global_load_lds(
                (const __attribute__((address_space(1))) void*)(gs + eo + lane * 8),
                (__attribute__((address_space(3))) void*)(ld + eo), 16, 0, 0);
        }
    };

    f32x4 acc[8][4];                    // [code frag fi][token frag fj]
    #pragma unroll
    for (int fi = 0; fi < 8; ++fi)
        #pragma unroll
        for (int fj = 0; fj < 4; ++fj)
            acc[fi][fj] = (f32x4){0.f, 0.f, 0.f, 0.f};

    const int tHalf = wc >> 1;
    const int tRow0 = (wc & 1) * 64 + c15;

    // prologue: steps 0,1 in flight; wait step0 arrival
    stage(0, 0);
    stage(1, 1);
    asm volatile("s_waitcnt vmcnt(8)" ::: "memory");
    __builtin_amdgcn_s_barrier();

    #pragma unroll
    for (int t = 0; t < 4; ++t) {
        const int bf = t & 1;
        const unsigned short* sTb = &sT[bf][tHalf * 8192];
        const unsigned short* sCb = &sC[bf][wr * 8192];
        #pragma unroll
        for (int ks = 0; ks < 2; ++ks) {
            const int ca = (ks * 4 + q) * 128;
            short8 tfr[4];
            #pragma unroll
            for (int fj = 0; fj < 4; ++fj)
                tfr[fj] = *(const short8*)(sTb + (size_t)(ca + tRow0 + fj * 16) * 8);
            #pragma unroll
            for (int fih = 0; fih < 2; ++fih) {
                short8 cfr[4];
                #pragma unroll
                for (int f = 0; f < 4; ++f)
                    cfr[f] = *(const short8*)(sCb + (size_t)(ca + fih * 64 + f * 16 + c15) * 8);
                __builtin_amdgcn_s_barrier();           // phase-align (role split)
                __builtin_amdgcn_s_setprio(1);
                #pragma unroll
                for (int f = 0; f < 4; ++f)
                    #pragma unroll
                    for (int fj = 0; fj < 4; ++fj)
                        acc[fih * 4 + f][fj] = __builtin_amdgcn_mfma_f32_16x16x32_bf16(
                            cfr[f], tfr[fj], acc[fih * 4 + f][fj], 0, 0, 0);
                __builtin_amdgcn_s_setprio(0);
                __builtin_amdgcn_s_barrier();
            }
        }
        // step boundary: all waves done reading buf[bf] -> safe to recycle it.
        asm volatile("s_waitcnt lgkmcnt(0)" ::: "memory");
        __builtin_amdgcn_s_barrier();
        if (t == 0)      { stage(0, 2); asm volatile("s_waitcnt vmcnt(8)" ::: "memory"); }
        else if (t == 1) { stage(1, 3); asm volatile("s_waitcnt vmcnt(8)" ::: "memory"); }
        else if (t == 2) {              asm volatile("s_waitcnt vmcnt(0)" ::: "memory"); }
        __builtin_amdgcn_s_barrier();
    }

    // epilogue: per-32-code-group max. C layout: col=lane&15=token,
    // row=q*4+rg=code (within frag) -> group of 32 codes = 2 frags, reduce
    // 8 in-thread values + 2 shfl over q. fp32 max is order-independent.
    f32x4 wq4[8];
    #pragma unroll
    for (int fi = 0; fi < 8; ++fi)
        wq4[fi] = *(const f32x4*)(&swsq[wr * 128 + fi * 16 + q * 4]);

    #pragma unroll
    for (int fj = 0; fj < 4; ++fj) {
        float vg[4];
        #pragma unroll
        for (int gl = 0; gl < 4; ++gl) {
            float v = -INFINITY;
            #pragma unroll
            for (int f2 = 0; f2 < 2; ++f2) {
                const int fi = gl * 2 + f2;
                #pragma unroll
                for (int rg = 0; rg < 4; ++rg)
                    v = fmaxf(v, 2.0f * acc[fi][fj][rg] - wq4[fi][rg]);
            }
            v = fmaxf(v, __shfl_xor(v, 16));
            v = fmaxf(v, __shfl_xor(v, 32));
            vg[gl] = v;
        }
        const float val = (q == 0) ? vg[0] : (q == 1) ? vg[1] : (q == 2) ? vg[2] : vg[3];
        rowbuf[wr * 4 + q][wc * 64 + fj * 16 + c15] = val;
    }
    __syncthreads();
    {
        const int row = tid >> 1, half = tid & 1;
        float4 o;
        o.x = rowbuf[half * 4 + 0][row];
        o.y = rowbuf[half * 4 + 1][row];
        o.z = rowbuf[half * 4 + 2][row];
        o.w = rowbuf[half * 4 + 3][row];
        *(float4*)(cmax + (size_t)(mt * 256 + row) * 256 + kt * 8 + half * 4) = o;
    }
}

// ---------------------------------------------------------------------------
// Kernel 4: candidate build, bucketed by group. One wave per token.
__global__ __launch_bounds__(256) void cand_kernel(const float* __restrict__ cmax,
                                                   unsigned int* __restrict__ gseg,
                                                   int* __restrict__ gcnt,
                                                   unsigned long long* __restrict__ packed,
                                                   int* __restrict__ nflag,
                                                   int* __restrict__ oflow) {
    const int t = threadIdx.x, wv = t >> 6, lane = t & 63;
    const int n = blockIdx.x * 4 + wv;
    float4 c4 = *(const float4*)(cmax + (size_t)n * 256 + lane * 4);
    float lm = fmaxf(fmaxf(c4.x, c4.y), fmaxf(c4.z, c4.w));
    #pragma unroll
    for (int off = 1; off <= 32; off <<= 1) lm = fmaxf(lm, __shfl_xor(lm, off));
    const float thresh = lm - MARGIN;
    if (lane == 0) { packed[n] = 0ull; nflag[n] = 0; }
    float g4[4] = {c4.x, c4.y, c4.z, c4.w};
    #pragma unroll
    for (int j = 0; j < 4; ++j) {
        int g = lane * 4 + j;
        if (g4[j] >= thresh) {
            int pos = atomicAdd(&gcnt[g], 1);
            if (pos < GCAP) gseg[(size_t)g * GCAP + pos] = (unsigned int)n;
            else { nflag[n] = 1; atomicAdd(oflow, 1); }
        }
    }
}

// ---------------------------------------------------------------------------
// Kernel 5: group-centric exact fp32 rescore, 8 blocks per group
// (load-balance the big groups). Per-token fp32 chain is FROZEN (same dot
// order as R4/R7); atomicMax merge is order-independent, so the token->block
// assignment change cannot alter results.
__global__ __launch_bounds__(256) void rescore_kernel(const float* __restrict__ zn,
                                                      const float* __restrict__ W,
                                                      const float* __restrict__ wsqv,
                                                      const float* __restrict__ znsq,
                                                      const unsigned int* __restrict__ gseg,
                                                      const int* __restrict__ gcnt,
                                                      unsigned long long* __restrict__ packed) {
    __shared__ float sW[32 * 260];       // stride 260: spread banks
    __shared__ float znr[4][2][256];     // per-wave, per-half token rows

    const int t = threadIdx.x;
    const int g   = blockIdx.x >> 3;
    const int sub = blockIdx.x & 7;
    int cnt = gcnt[g]; if (cnt > GCAP) cnt = GCAP;
    if (cnt <= sub * 8) return;          // this sub-block has no tokens

    {   // stage W group (contiguous 32 KB chunk of W)
        int c = t >> 3, i = t & 7;
        const float4* src = (const float4*)(W + (size_t)g * 8192 + c * 256 + i * 32);
        #pragma unroll
        for (int j = 0; j < 8; ++j)
            *(float4*)(sW + c * 260 + i * 32 + j * 4) = src[j];
    }
    __syncthreads();

    const int wv = t >> 6, lane = t & 63;
    const int h = lane >> 5, c = lane & 31;
    const int k = g * 32 + c;
    const float wq = wsqv[k];
    const float4* wrow = (const float4*)(sW + c * 260);

    for (int base = (sub * 4 + wv) * 2; base < cnt; base += RSPLIT * 8) {
        int idx = base + h; if (idx >= cnt) idx = base;
        int n = (int)gseg[(size_t)g * GCAP + idx];
        *(float4*)(&znr[wv][h][c * 8])     = *(const float4*)(zn + (size_t)n * DD + c * 8);
        *(float4*)(&znr[wv][h][c * 8 + 4]) = *(const float4*)(zn + (size_t)n * DD + c * 8 + 4);
        float d = 0.f;
        #pragma unroll
        for (int j = 0; j < 64; ++j) {
            float4 wv4 = wrow[j];
            float4 zv  = *(const float4*)(&znr[wv][h][j * 4]);
            d += wv4.x * zv.x + wv4.y * zv.y + wv4.z * zv.z + wv4.w * zv.w;
        }
        float s = (-znsq[n] - wq) + 2.0f * d;
        unsigned long long key = pack_key(s, k);
        #pragma unroll
        for (int off = 1; off <= 16; off <<= 1) {
            unsigned long long ok = __shfl_xor(key, off);
            if (ok > key) key = ok;
        }
        if (c == 0) atomicMax(packed + n, key);
    }
}

// ---------------------------------------------------------------------------
// Kernel 6: fullscan fallback for overflow-flagged tokens (early-exit normally).
__global__ __launch_bounds__(256) void fullscan_kernel(const float* __restrict__ zn,
                                                       const float* __restrict__ W,
                                                       const float* __restrict__ wsqv,
                                                       const float* __restrict__ znsq,
                                                       const int* __restrict__ nflag,
                                                       const int* __restrict__ oflow,
                                                       unsigned long long* __restrict__ packed) {
    if (*oflow == 0) return;
    const int t = threadIdx.x, wv = t >> 6, lane = t & 63;
    const int code = lane >> 1, part = lane & 1;
    for (int n = blockIdx.x * 4 + wv; n < NN; n += gridDim.x * 4) {
        if (!nflag[n]) continue;
        float zsq = znsq[n];
        unsigned long long best = 0ull;
        for (int gg = 0; gg < 256; ++gg) {
            int k = gg * 32 + code;
            const float4* wrp = (const float4*)(W + (size_t)k * DD + part * 128);
            const float4* zrp = (const float4*)(zn + (size_t)n * DD + part * 128);
            float d = 0.f;
            #pragma unroll
            for (int jj = 0; jj < 32; ++jj) {
                float4 a = zrp[jj], b = wrp[jj];
                d += a.x * b.x + a.y * b.y + a.z * b.z + a.w * b.w;
            }
            d += __shfl_xor(d, 1);
            unsigned long long key = pack_key((-zsq - wsqv[k]) + 2.0f * d, k);
            if (key > best) best = key;
        }
        #pragma unroll
        for (int off = 1; off <= 32; off <<= 1) {
            unsigned long long ok = __shfl_xor(best, off);
            if (ok > best) best = ok;
        }
        if (lane == 0) atomicMax(packed + n, best);
    }
}

// ---------------------------------------------------------------------------
// Kernel 7: fused finalize + gather. Decodes packed -> idx/loss, then gathers
// z_q coalesced over hw.
__global__ __launch_bounds__(256) void gatherfin_kernel(const float* __restrict__ W,
                                                        const unsigned long long* __restrict__ packed,
                                                        float* __restrict__ idxf,
                                                        float* __restrict__ partials,
                                                        float* __restrict__ zq) {
    __shared__ int sbk[64];
    const int t   = threadIdx.x;
    const int b   = blockIdx.x >> 4;
    const int hw0 = (blockIdx.x & 15) * 64;
    if (t < 64) {
        int n = b * HW + hw0 + t;
        unsigned long long key = packed[n];
        int k = (int)((~(unsigned int)key) & 0x3FFFu);
        unsigned int o = (unsigned int)(key >> 32);
        unsigned int bits = (o & 0x80000000u) ? (o & 0x7FFFFFFFu) : ~o;
        float s = __uint_as_float(bits);
        sbk[t] = k;
        idxf[n] = (float)k;
        float cc = -s;
        #pragma unroll
        for (int off = 32; off; off >>= 1) cc += __shfl_down(cc, off);
        if (t == 0) partials[blockIdx.x] = cc;
    }
    __syncthreads();
    const int hw  = t & 63;
    const int c0  = (t >> 6) * 4;
    const int row = sbk[hw];
    #pragma unroll
    for (int cg = 0; cg < 16; ++cg) {
        int c = cg * 16 + c0;
        float4 v = *(const float4*)(W + (size_t)row * DD + c);
        size_t base = ((size_t)(b * CC + c) << 10) + hw0 + hw;
        zq[base]        = v.x;
        zq[base + 1024] = v.y;
        zq[base + 2048] = v.z;
        zq[base + 3072] = v.w;
    }
}

// ---------------------------------------------------------------------------
// Kernel 8: final loss = BETA * sum(256 partials) / (N*D)
__global__ __launch_bounds__(256) void loss_final_kernel(const float* __restrict__ partials,
                                                         float* __restrict__ out_loss) {
    __shared__ float wsum[4];
    const int t = threadIdx.x;
    float v = partials[t];
    #pragma unroll
    for (int off = 32; off; off >>= 1) v += __shfl_down(v, off);
    if ((t & 63) == 0) wsum[t >> 6] = v;
    __syncthreads();
    if (t == 0) {
        float tot = wsum[0] + wsum[1] + wsum[2] + wsum[3];
        *out_loss = 0.25f * (tot / (float)ZQ_SIZE);
    }
}

// ---------------------------------------------------------------------------
extern "C" void kernel_launch(void* const* d_in, const int* in_sizes, int n_in,
                              void* d_out, int out_size, void* d_ws, size_t ws_size,
                              hipStream_t stream) {
    const float* z = (const float*)d_in[0];   // [16,256,32,32]
    const float* W = (const float*)d_in[1];   // [8192,256]

    float* out   = (float*)d_out;
    float* zq    = out;                 // 4194304
    float* loss  = out + ZQ_SIZE;       // 1
    float* idxf  = out + ZQ_SIZE + 1;   // 16384 (idx as float)

    float* ws       = (float*)d_ws;
    float* zn       = ws;                         // 16 MB
    float* znsq     = zn + (size_t)NN * DD;       // 16384 f
    float* wsqv     = znsq + NN;                  // 8192 f
    float* partials = wsqv + KK;                  // 256 f
    int*   gcnt     = (int*)(partials + 256);     // 256 i
    int*   oflow    = gcnt + 256;                 // 1 (pad 64)
    int*   nflag    = oflow + 64;                 // 16384 i
    unsigned short* zb = (unsigned short*)(nflag + NN);       // 8 MB
    unsigned short* wb = zb + (size_t)NN * DD;                // 4 MB
    float* cmax     = (float*)(wb + (size_t)KK * DD);         // 16 MB
    unsigned int* gseg = (unsigned int*)(cmax + (size_t)NN * 256); // 8 MB
    unsigned long long* packed = (unsigned long long*)(gseg + (size_t)256 * GCAP); // 128 KB

    wsqwb_kernel     <<<KK / 4, 256, 0, stream>>>(W, wsqv, wb, gcnt, oflow);
    normalize_kernel <<<BB * 16, 256, 0, stream>>>(z, zn, znsq, zb);
    score_kernel     <<<(NN / 256) * (KK / 256), 512, 0, stream>>>(zb, wb, wsqv, cmax);
    cand_kernel      <<<NN / 4, 256, 0, stream>>>(cmax, gseg, gcnt, packed, nflag, oflow);
    rescore_kernel   <<<256 * RSPLIT, 256, 0, stream>>>(zn, W, wsqv, znsq, gseg, gcnt, packed);
    fullscan_kernel  <<<64, 256, 0, stream>>>(zn, W, wsqv, znsq, nflag, oflow, packed);
    gatherfin_kernel <<<BB * 16, 256, 0, stream>>>(W, packed, idxf, partials, zq);
    loss_final_kernel<<<1, 256, 0, stream>>>(partials, loss);
}

// Round 2
// 233.164 us; speedup vs baseline: 1.0220x; 1.0220x over previous
//
#include <hip/hip_runtime.h>
#include <math.h>

// Problem constants
#define BB   16
#define CC   256
#define HW   1024          // 32*32
#define NN   16384         // BB*HW tokens
#define DD   256           // dim
#define KK   8192          // codes
#define ZQ_SIZE 4194304    // 16*256*1024
#define MARGIN 0.017f      // rigorous bf16-score error envelope (bound 0.0156)
#define GCAP 8192          // per-group candidate-token capacity (overflow -> fullscan)
#define RSPLIT 8           // rescore blocks per group (load-balance)

typedef __attribute__((ext_vector_type(8))) short short8;  // 8 bf16 (4 VGPRs)
typedef __attribute__((ext_vector_type(4))) float f32x4;

static __device__ inline unsigned short f2bf(float x) {
    unsigned int u = __float_as_uint(x);
    unsigned int r = (u + 0x7fff + ((u >> 16) & 1)) >> 16;   // RNE
    return (unsigned short)r;
}

static __device__ inline unsigned long long pack_key(float s, int k) {
    unsigned int bits = __float_as_uint(s);
    unsigned int o = (bits & 0x80000000u) ? ~bits : (bits | 0x80000000u);
    return ((unsigned long long)o << 32) | (unsigned int)(~k);
}

// ---------------------------------------------------------------------------
// Kernel 1: wsq (VERBATIM R4 chain — FROZEN: knife-edge fp32 argmax contract;
// R5/R6 reordered this sum and deterministically flipped one token's idx)
// + wb bf16 blob (verbatim body, blocks 0..1023) fused in one W pass.
// Block 0 zeroes gcnt/oflow.
__global__ __launch_bounds__(256) void wsqwb_kernel(const float* __restrict__ W,
                                                    float* __restrict__ wsq,
                                                    unsigned short* __restrict__ wb,
                                                    int* __restrict__ gcnt,
                                                    int* __restrict__ oflow) {
    if (blockIdx.x == 0) {
        gcnt[threadIdx.x] = 0;
        if (threadIdx.x == 0) *oflow = 0;
    }
    {   // --- wsq part: FROZEN summation order (float4 at lane*4, 64-lane tree)
        const int lane = threadIdx.x & 63;
        const int k = blockIdx.x * 4 + (threadIdx.x >> 6);
        float4 v = *(const float4*)(W + (size_t)k * DD + lane * 4);
        float s = v.x * v.x + v.y * v.y + v.z * v.z + v.w * v.w;
        #pragma unroll
        for (int off = 32; off; off >>= 1) s += __shfl_down(s, off);
        if (lane == 0) wsq[k] = s;
    }
    if (blockIdx.x < 1024) {   // --- wb part: verbatim R4 wb_convert body
        const int ch = blockIdx.x * 256 + threadIdx.x;     // 0..262143
        const int c = (ch >> 7) & 7;
        const int r = ch & 127;
        const int kt = ch >> 12, dc = (ch >> 10) & 3;
        const int k = kt * 128 + r;
        const int d0 = dc * 64 + c * 8;
        const float4 v0 = *(const float4*)(W + (size_t)k * DD + d0);
        const float4 v1 = *(const float4*)(W + (size_t)k * DD + d0 + 4);
        uint4 out;
        out.x = (unsigned int)f2bf(v0.x) | ((unsigned int)f2bf(v0.y) << 16);
        out.y = (unsigned int)f2bf(v0.z) | ((unsigned int)f2bf(v0.w) << 16);
        out.z = (unsigned int)f2bf(v1.x) | ((unsigned int)f2bf(v1.y) << 16);
        out.w = (unsigned int)f2bf(v1.z) | ((unsigned int)f2bf(v1.w) << 16);
        *(uint4*)(wb + (size_t)ch * 8) = out;
    }
}

// ---------------------------------------------------------------------------
// Kernel 2: transpose + l2-normalize. Same tile cells / sum order / division
// as the passing R7 version (bit-identical values); only the z-load is
// vectorized to float4 (hw-contiguous).
__global__ __launch_bounds__(256) void normalize_kernel(const float* __restrict__ z,
                                                        float* __restrict__ zn,
                                                        float* __restrict__ znsq,
                                                        unsigned short* __restrict__ zb) {
    __shared__ float tile[64][257];
    __shared__ float s_nrm[64];
    const int t   = threadIdx.x;
    const int b   = blockIdx.x >> 4;
    const int hw0 = (blockIdx.x & 15) * 64;

    #pragma unroll
    for (int cg = 0; cg < 16; ++cg) {
        int c  = cg * 16 + (t >> 4);
        int hw = (t & 15) * 4;
        float4 v = *(const float4*)(z + ((size_t)(b * CC + c) << 10) + hw0 + hw);
        tile[hw + 0][c] = v.x;
        tile[hw + 1][c] = v.y;
        tile[hw + 2][c] = v.z;
        tile[hw + 3][c] = v.w;
    }
    __syncthreads();
    if (t < 64) {
        float s = 0.f;
        #pragma unroll 8
        for (int c = 0; c < 256; ++c) { float v = tile[t][c]; s += v * v; }
        float nrm = sqrtf(s);
        nrm = fmaxf(nrm, 1e-12f);
        s_nrm[t] = nrm;
        znsq[(size_t)b * HW + hw0 + t] = s / (nrm * nrm);
    }
    __syncthreads();
    const int n0 = b * HW + hw0;           // multiple of 64
    for (int r = 0; r < 64; ++r) {
        zn[(size_t)(n0 + r) * DD + t] = tile[r][t] / s_nrm[r];
    }
    const int r    = t & 63;
    const int mt   = n0 >> 7;
    const int rg   = (n0 & 127) + r;
    const float nrm = s_nrm[r];
    #pragma unroll
    for (int loop = 0; loop < 8; ++loop) {
        int comb = loop * 4 + (t >> 6);    // 0..31
        int dc = comb >> 3, c = comb & 7;
        int d0 = dc * 64 + c * 8;
        uint4 out;
        out.x = (unsigned int)f2bf(tile[r][d0 + 0] / nrm) | ((unsigned int)f2bf(tile[r][d0 + 1] / nrm) << 16);
        out.y = (unsigned int)f2bf(tile[r][d0 + 2] / nrm) | ((unsigned int)f2bf(tile[r][d0 + 3] / nrm) << 16);
        out.z = (unsigned int)f2bf(tile[r][d0 + 4] / nrm) | ((unsigned int)f2bf(tile[r][d0 + 5] / nrm) << 16);
        out.w = (unsigned int)f2bf(tile[r][d0 + 6] / nrm) | ((unsigned int)f2bf(tile[r][d0 + 7] / nrm) << 16);
        *(uint4*)(zb + (size_t)(mt * 4 + dc) * 8192 + (size_t)(c * 128 + rg) * 8) = out;
    }
}

// ---------------------------------------------------------------------------
// Kernel 3: MFMA scorer, 256x256 tile, 8 waves. Faithful m201 8-phase port:
// per phase {ds_read subtile || 2x global_load_lds prefetch} -> s_barrier ->
// lgkmcnt(0) -> setprio(1) -> 16 MFMA -> setprio(0) -> s_barrier.
// Staging spread 2 loads/phase; ONE vmcnt(0)+barrier per K-step boundary;
// prologue prefetches both buffers with counted vmcnt(8).
// Per-element MFMA accumulation order over (dc, ks) is IDENTICAL to the
// 128^2 version -> cmax bit-identical (addressing/epilogue verified Round 1).
__global__ __launch_bounds__(512, 2) void score_kernel(const unsigned short* __restrict__ zb,
                                                       const unsigned short* __restrict__ wb,
                                                       const float* __restrict__ wsqv,
                                                       float* __restrict__ cmax) {
    __shared__ __align__(16) unsigned short sT[2][16384];  // tokens: [dbuf][2 halves x 8192]
    __shared__ __align__(16) unsigned short sC[2][16384];  // codes
    __shared__ float rowbuf[8][260];                       // [group col][token] (bank-spread)
    __shared__ __align__(16) float swsq[256];

    const int tid  = threadIdx.x;
    const int w    = tid >> 6;          // 0..7
    const int lane = tid & 63;
    const int wr   = w >> 2;            // code half (128 codes)
    const int wc   = w & 3;             // token quarter (64 tokens)
    const int q    = lane >> 4, c15 = lane & 15;
    const int kt   = blockIdx.x & 31;   // code tile of 256
    const int mt   = blockIdx.x >> 5;   // token tile of 256
    const int mtb  = mt * 8;            // zb blob base
    const int ktb  = kt * 8;            // wb blob base

    if (tid < 256) swsq[tid] = wsqv[kt * 256 + tid];

    // staging: wave pair -> one 16KB blob; issue 2 of the 8 per-thread loads.
    const int sh = (w >> 1) & 1;        // blob half (rows 0..127 vs 128..255)
    auto stage2 = [&](int bf, int dc, int i0) {
        const unsigned short* gs = (w < 4)
            ? (zb + (size_t)(mtb + sh * 4 + dc) * 8192)
            : (wb + (size_t)(ktb + sh * 4 + dc) * 8192);
        unsigned short* ld = (w < 4) ? &sT[bf][sh * 8192] : &sC[bf][sh * 8192];
        #pragma unroll
        for (int i = i0; i < i0 + 2; ++i) {
            const int eo = ((w & 1) * 8 + i) << 9;   // shorts
            __builtin_amdgcn_global_load_lds(
                (const __attribute__((address_space(1))) void*)(gs + eo + lane * 8),
                (__attribute__((address_space(3))) void*)(ld + eo), 16, 0, 0);
        }
    };

    f32x4 acc[8][4];                    // [code frag fi][token frag fj]
    #pragma unroll
    for (int fi = 0; fi < 8; ++fi)
        #pragma unroll
        for (int fj = 0; fj < 4; ++fj)
            acc[fi][fj] = (f32x4){0.f, 0.f, 0.f, 0.f};

    const int tHalf = wc >> 1;
    const int tRow0 = (wc & 1) * 64 + c15;

    // prologue: stage K-step 0 -> buf0, K-step 1 -> buf1 (both buffers free);
    // wait only step0's 8 loads (counted vmcnt), publish, go.
    stage2(0, 0, 0); stage2(0, 0, 2); stage2(0, 0, 4); stage2(0, 0, 6);
    stage2(1, 1, 0); stage2(1, 1, 2); stage2(1, 1, 4); stage2(1, 1, 6);
    asm volatile("s_waitcnt vmcnt(8)" ::: "memory");
    __builtin_amdgcn_s_barrier();

    #pragma unroll
    for (int t = 0; t < 4; ++t) {
        const int bf = t & 1;
        const unsigned short* sTb = &sT[bf][tHalf * 8192];
        const unsigned short* sCb = &sC[bf][wr * 8192];
        short8 tfr[2][4];               // [ks][fj] — lives across the 4 phases
        #pragma unroll
        for (int p = 0; p < 4; ++p) {
            // --- phase p: reads for THIS phase's 16 MFMA ---
            if (p == 0) {
                #pragma unroll
                for (int ks = 0; ks < 2; ++ks)
                    #pragma unroll
                    for (int fj = 0; fj < 4; ++fj)
                        tfr[ks][fj] = *(const short8*)(sTb +
                            (size_t)((ks * 4 + q) * 128 + tRow0 + fj * 16) * 8);
            }
            short8 cfr[2][2];           // [ks][f], fi = p*2 + f
            #pragma unroll
            for (int ks = 0; ks < 2; ++ks)
                #pragma unroll
                for (int f = 0; f < 2; ++f)
                    cfr[ks][f] = *(const short8*)(sCb +
                        (size_t)((ks * 4 + q) * 128 + p * 32 + f * 16 + c15) * 8);
            // --- prefetch spread: 2 global_load_lds per phase ---
            if (t == 1)      stage2(0, 2, p * 2);   // step2 -> buf0
            else if (t == 2) stage2(1, 3, p * 2);   // step3 -> buf1
            // --- phase align -> wait reads -> MFMA cluster ---
            __builtin_amdgcn_s_barrier();
            asm volatile("s_waitcnt lgkmcnt(0)" ::: "memory");
            __builtin_amdgcn_sched_barrier(0);
            __builtin_amdgcn_s_setprio(1);
            #pragma unroll
            for (int ks = 0; ks < 2; ++ks)
                #pragma unroll
                for (int f = 0; f < 2; ++f)
                    #pragma unroll
                    for (int fj = 0; fj < 4; ++fj)
                        acc[p * 2 + f][fj] = __builtin_amdgcn_mfma_f32_16x16x32_bf16(
                            cfr[ks][f], tfr[ks][fj], acc[p * 2 + f][fj], 0, 0, 0);
            __builtin_amdgcn_s_setprio(0);
            __builtin_amdgcn_s_barrier();
        }
        // --- K-step boundary: drain own staging loads, publish buffer ---
        if (t < 3) {
            asm volatile("s_waitcnt vmcnt(0)" ::: "memory");
            __builtin_amdgcn_s_barrier();
        }
    }

    // epilogue: per-32-code-group max (verified Round 1; fp32 max is
    // order-independent; cmax feeds MARGIN-buffered selection anyway).
    f32x4 wq4[8];
    #pragma unroll
    for (int fi = 0; fi < 8; ++fi)
        wq4[fi] = *(const f32x4*)(&swsq[wr * 128 + fi * 16 + q * 4]);

    #pragma unroll
    for (int fj = 0; fj < 4; ++fj) {
        float vg[4];
        #pragma unroll
        for (int gl = 0; gl < 4; ++gl) {
            float v = -INFINITY;
            #pragma unroll
            for (int f2 = 0; f2 < 2; ++f2) {
                const int fi = gl * 2 + f2;
                #pragma unroll
                for (int rg = 0; rg < 4; ++rg)
                    v = fmaxf(v, 2.0f * acc[fi][fj][rg] - wq4[fi][rg]);
            }
            v = fmaxf(v, __shfl_xor(v, 16));
            v = fmaxf(v, __shfl_xor(v, 32));
            vg[gl] = v;
        }
        const float val = (q == 0) ? vg[0] : (q == 1) ? vg[1] : (q == 2) ? vg[2] : vg[3];
        rowbuf[wr * 4 + q][wc * 64 + fj * 16 + c15] = val;
    }
    __syncthreads();
    {
        const int row = tid >> 1, half = tid & 1;
        float4 o;
        o.x = rowbuf[half * 4 + 0][row];
        o.y = rowbuf[half * 4 + 1][row];
        o.z = rowbuf[half * 4 + 2][row];
        o.w = rowbuf[half * 4 + 3][row];
        *(float4*)(cmax + (size_t)(mt * 256 + row) * 256 + kt * 8 + half * 4) = o;
    }
}

// ---------------------------------------------------------------------------
// Kernel 4: candidate build, bucketed by group. One wave per token.
__global__ __launch_bounds__(256) void cand_kernel(const float* __restrict__ cmax,
                                                   unsigned int* __restrict__ gseg,
                                                   int* __restrict__ gcnt,
                                                   unsigned long long* __restrict__ packed,
                                                   int* __restrict__ nflag,
                                                   int* __restrict__ oflow) {
    const int t = threadIdx.x, wv = t >> 6, lane = t & 63;
    const int n = blockIdx.x * 4 + wv;
    float4 c4 = *(const float4*)(cmax + (size_t)n * 256 + lane * 4);
    float lm = fmaxf(fmaxf(c4.x, c4.y), fmaxf(c4.z, c4.w));
    #pragma unroll
    for (int off = 1; off <= 32; off <<= 1) lm = fmaxf(lm, __shfl_xor(lm, off));
    const float thresh = lm - MARGIN;
    if (lane == 0) { packed[n] = 0ull; nflag[n] = 0; }
    float g4[4] = {c4.x, c4.y, c4.z, c4.w};
    #pragma unroll
    for (int j = 0; j < 4; ++j) {
        int g = lane * 4 + j;
        if (g4[j] >= thresh) {
            int pos = atomicAdd(&gcnt[g], 1);
            if (pos < GCAP) gseg[(size_t)g * GCAP + pos] = (unsigned int)n;
            else { nflag[n] = 1; atomicAdd(oflow, 1); }
        }
    }
}

// ---------------------------------------------------------------------------
// Kernel 5: group-centric exact fp32 rescore, 8 blocks per group
// (load-balance the big groups). Per-token fp32 chain is FROZEN (same dot
// order as R4/R7); atomicMax merge is order-independent, so the token->block
// assignment change cannot alter results.
__global__ __launch_bounds__(256) void rescore_kernel(const float* __restrict__ zn,
                                                      const float* __restrict__ W,
                                                      const float* __restrict__ wsqv,
                                                      const float* __restrict__ znsq,
                                                      const unsigned int* __restrict__ gseg,
                                                      const int* __restrict__ gcnt,
                                                      unsigned long long* __restrict__ packed) {
    __shared__ float sW[32 * 260];       // stride 260: spread banks
    __shared__ float znr[4][2][256];     // per-wave, per-half token rows

    const int t = threadIdx.x;
    const int g   = blockIdx.x >> 3;
    const int sub = blockIdx.x & 7;
    int cnt = gcnt[g]; if (cnt > GCAP) cnt = GCAP;
    if (cnt <= sub * 8) return;          // this sub-block has no tokens

    {   // stage W group (contiguous 32 KB chunk of W)
        int c = t >> 3, i = t & 7;
        const float4* src = (const float4*)(W + (size_t)g * 8192 + c * 256 + i * 32);
        #pragma unroll
        for (int j = 0; j < 8; ++j)
            *(float4*)(sW + c * 260 + i * 32 + j * 4) = src[j];
    }
    __syncthreads();

    const int wv = t >> 6, lane = t & 63;
    const int h = lane >> 5, c = lane & 31;
    const int k = g * 32 + c;
    const float wq = wsqv[k];
    const float4* wrow = (const float4*)(sW + c * 260);

    for (int base = (sub * 4 + wv) * 2; base < cnt; base += RSPLIT * 8) {
        int idx = base + h; if (idx >= cnt) idx = base;
        int n = (int)gseg[(size_t)g * GCAP + idx];
        *(float4*)(&znr[wv][h][c * 8])     = *(const float4*)(zn + (size_t)n * DD + c * 8);
        *(float4*)(&znr[wv][h][c * 8 + 4]) = *(const float4*)(zn + (size_t)n * DD + c * 8 + 4);
        float d = 0.f;
        #pragma unroll
        for (int j = 0; j < 64; ++j) {
            float4 wv4 = wrow[j];
            float4 zv  = *(const float4*)(&znr[wv][h][j * 4]);
            d += wv4.x * zv.x + wv4.y * zv.y + wv4.z * zv.z + wv4.w * zv.w;
        }
        float s = (-znsq[n] - wq) + 2.0f * d;
        unsigned long long key = pack_key(s, k);
        #pragma unroll
        for (int off = 1; off <= 16; off <<= 1) {
            unsigned long long ok = __shfl_xor(key, off);
            if (ok > key) key = ok;
        }
        if (c == 0) atomicMax(packed + n, key);
    }
}

// ---------------------------------------------------------------------------
// Kernel 6: fullscan fallback for overflow-flagged tokens (early-exit normally).
__global__ __launch_bounds__(256) void fullscan_kernel(const float* __restrict__ zn,
                                                       const float* __restrict__ W,
                                                       const float* __restrict__ wsqv,
                                                       const float* __restrict__ znsq,
                                                       const int* __restrict__ nflag,
                                                       const int* __restrict__ oflow,
                                                       unsigned long long* __restrict__ packed) {
    if (*oflow == 0) return;
    const int t = threadIdx.x, wv = t >> 6, lane = t & 63;
    const int code = lane >> 1, part = lane & 1;
    for (int n = blockIdx.x * 4 + wv; n < NN; n += gridDim.x * 4) {
        if (!nflag[n]) continue;
        float zsq = znsq[n];
        unsigned long long best = 0ull;
        for (int gg = 0; gg < 256; ++gg) {
            int k = gg * 32 + code;
            const float4* wrp = (const float4*)(W + (size_t)k * DD + part * 128);
            const float4* zrp = (const float4*)(zn + (size_t)n * DD + part * 128);
            float d = 0.f;
            #pragma unroll
            for (int jj = 0; jj < 32; ++jj) {
                float4 a = zrp[jj], b = wrp[jj];
                d += a.x * b.x + a.y * b.y + a.z * b.z + a.w * b.w;
            }
            d += __shfl_xor(d, 1);
            unsigned long long key = pack_key((-zsq - wsqv[k]) + 2.0f * d, k);
            if (key > best) best = key;
        }
        #pragma unroll
        for (int off = 1; off <= 32; off <<= 1) {
            unsigned long long ok = __shfl_xor(best, off);
            if (ok > best) best = ok;
        }
        if (lane == 0) atomicMax(packed + n, best);
    }
}

// ---------------------------------------------------------------------------
// Kernel 7: fused finalize + gather. Decodes packed -> idx/loss, then gathers
// z_q coalesced over hw.
__global__ __launch_bounds__(256) void gatherfin_kernel(const float* __restrict__ W,
                                                        const unsigned long long* __restrict__ packed,
                                                        float* __restrict__ idxf,
                                                        float* __restrict__ partials,
                                                        float* __restrict__ zq) {
    __shared__ int sbk[64];
    const int t   = threadIdx.x;
    const int b   = blockIdx.x >> 4;
    const int hw0 = (blockIdx.x & 15) * 64;
    if (t < 64) {
        int n = b * HW + hw0 + t;
        unsigned long long key = packed[n];
        int k = (int)((~(unsigned int)key) & 0x3FFFu);
        unsigned int o = (unsigned int)(key >> 32);
        unsigned int bits = (o & 0x80000000u) ? (o & 0x7FFFFFFFu) : ~o;
        float s = __uint_as_float(bits);
        sbk[t] = k;
        idxf[n] = (float)k;
        float cc = -s;
        #pragma unroll
        for (int off = 32; off; off >>= 1) cc += __shfl_down(cc, off);
        if (t == 0) partials[blockIdx.x] = cc;
    }
    __syncthreads();
    const int hw  = t & 63;
    const int c0  = (t >> 6) * 4;
    const int row = sbk[hw];
    #pragma unroll
    for (int cg = 0; cg < 16; ++cg) {
        int c = cg * 16 + c0;
        float4 v = *(const float4*)(W + (size_t)row * DD + c);
        size_t base = ((size_t)(b * CC + c) << 10) + hw0 + hw;
        zq[base]        = v.x;
        zq[base + 1024] = v.y;
        zq[base + 2048] = v.z;
        zq[base + 3072] = v.w;
    }
}

// ---------------------------------------------------------------------------
// Kernel 8: final loss = BETA * sum(256 partials) / (N*D)
__global__ __launch_bounds__(256) void loss_final_kernel(const float* __restrict__ partials,
                                                         float* __restrict__ out_loss) {
    __shared__ float wsum[4];
    const int t = threadIdx.x;
    float v = partials[t];
    #pragma unroll
    for (int off = 32; off; off >>= 1) v += __shfl_down(v, off);
    if ((t & 63) == 0) wsum[t >> 6] = v;
    __syncthreads();
    if (t == 0) {
        float tot = wsum[0] + wsum[1] + wsum[2] + wsum[3];
        *out_loss = 0.25f * (tot / (float)ZQ_SIZE);
    }
}

// ---------------------------------------------------------------------------
extern "C" void kernel_launch(void* const* d_in, const int* in_sizes, int n_in,
                              void* d_out, int out_size, void* d_ws, size_t ws_size,
                              hipStream_t stream) {
    const float* z = (const float*)d_in[0];   // [16,256,32,32]
    const float* W = (const float*)d_in[1];   // [8192,256]

    float* out   = (float*)d_out;
    float* zq    = out;                 // 4194304
    float* loss  = out + ZQ_SIZE;       // 1
    float* idxf  = out + ZQ_SIZE + 1;   // 16384 (idx as float)

    float* ws       = (float*)d_ws;
    float* zn       = ws;                         // 16 MB
    float* znsq     = zn + (size_t)NN * DD;       // 16384 f
    float* wsqv     = znsq + NN;                  // 8192 f
    float* partials = wsqv + KK;                  // 256 f
    int*   gcnt     = (int*)(partials + 256);     // 256 i
    int*   oflow    = gcnt + 256;                 // 1 (pad 64)
    int*   nflag    = oflow + 64;                 // 16384 i
    unsigned short* zb = (unsigned short*)(nflag + NN);       // 8 MB
    unsigned short* wb = zb + (size_t)NN * DD;                // 4 MB
    float* cmax     = (float*)(wb + (size_t)KK * DD);         // 16 MB
    unsigned int* gseg = (unsigned int*)(cmax + (size_t)NN * 256); // 8 MB
    unsigned long long* packed = (unsigned long long*)(gseg + (size_t)256 * GCAP); // 128 KB

    wsqwb_kernel     <<<KK / 4, 256, 0, stream>>>(W, wsqv, wb, gcnt, oflow);
    normalize_kernel <<<BB * 16, 256, 0, stream>>>(z, zn, znsq, zb);
    score_kernel     <<<(NN / 256) * (KK / 256), 512, 0, stream>>>(zb, wb, wsqv, cmax);
    cand_kernel      <<<NN / 4, 256, 0, stream>>>(cmax, gseg, gcnt, packed, nflag, oflow);
    rescore_kernel   <<<256 * RSPLIT, 256, 0, stream>>>(zn, W, wsqv, znsq, gseg, gcnt, packed);
    fullscan_kernel  <<<64, 256, 0, stream>>>(zn, W, wsqv, znsq, nflag, oflow, packed);
    gatherfin_kernel <<<BB * 16, 256, 0, stream>>>(W, packed, idxf, partials, zq);
    loss_final_kernel<<<1, 256, 0, stream>>>(partials, loss);
}